// Round 6
// baseline (125.749 us; speedup 1.0000x reference)
//
#include <hip/hip_runtime.h>

// ClusteringAffinity: out[n,c] = exp(-min_j (f[n]-W[c,j])^2 / 10) for c<100,
// out[n,100] = rw (pairwise-variance regularizer over the 500 centers).
//
// R6: single fused kernel, 320-thread blocks (5 waves):
//   waves 0-3, threads 0..199: distance cols (thread -> (row-half, col), 16 rows)
//   wave 4 (t 256..319): rw power sums (double, butterfly) -> writes col 100
//     into the tile; fully overlapped with distance compute, kills the
//     separate rw launch.
//   then one barrier, and the 32x101 tile streams out as contiguous aligned
//   16B nt stores (tile byte base = blk*12928 % 16 == 0) — the same address
//   pattern as the 6.4 TB/s harness fill.
// ROWS 64->32: LDS 12.9 KB -> 6 blocks/CU (30 waves) + finer compute/store
// interleave across blocks.
//
// rw via power sums over the 500 scalar centers:
//   S1 = sum_{i<j}(wi-wj)^2 = mc*p2 - p1^2
//   Sq = sum_{i<j}(wi-wj)^4 = mc*p4 - 4*p3*p1 + 3*p2^2
//   mu = S1/P, rw = Sq/P - mu^2, P = (mc^2-mc)/2

static constexpr int N_    = 262144;
static constexpr int C_    = 100;
static constexpr int M_    = 5;
static constexpr int COLS  = C_ + 1;       // 101
static constexpr int MC_   = C_ * M_;      // 500
static constexpr int ROWS  = 32;           // rows per tile/block
static constexpr int TILE  = ROWS * COLS;  // 3232 floats = 12928 B (16B-aligned tiles)
static constexpr int BLK   = 320;          // 5 waves
static constexpr float SIGMA_INV = 0.1f;

typedef float floatx4 __attribute__((ext_vector_type(4)));

__global__ __launch_bounds__(BLK)
void affinity_kernel(const float* __restrict__ f,
                     const float* __restrict__ W,
                     float* __restrict__ out) {
    __shared__ __align__(16) float tile[TILE];
    const int t  = threadIdx.x;
    const int n0 = blockIdx.x * ROWS;

    if (t < 200) {
        // ---- distance compute: thread -> (row-half rh, column c), 16 rows ----
        const int rh = (t >= C_) ? 1 : 0;
        const int c  = t - rh * C_;               // 0..99
        float* trow = tile + rh * 16 * COLS + c;

        // 16 consecutive f values: 4 aligned float4 loads (L1-broadcast)
        float fv[16];
        const float4* f4 = (const float4*)(f + n0 + rh * 16);
#pragma unroll
        for (int q = 0; q < 4; ++q) {
            const float4 v = f4[q];
            fv[q * 4 + 0] = v.x; fv[q * 4 + 1] = v.y;
            fv[q * 4 + 2] = v.z; fv[q * 4 + 3] = v.w;
        }
        const float w0 = W[c * M_ + 0];
        const float w1 = W[c * M_ + 1];
        const float w2 = W[c * M_ + 2];
        const float w3 = W[c * M_ + 3];
        const float w4 = W[c * M_ + 4];
#pragma unroll
        for (int i = 0; i < 16; ++i) {
            const float fk = fv[i];
            const float d0 = fk - w0, d1 = fk - w1, d2 = fk - w2,
                        d3 = fk - w3, d4 = fk - w4;
            const float m01 = fminf(d0 * d0, d1 * d1);
            const float m23 = fminf(d2 * d2, d3 * d3);
            const float mv  = fminf(fminf(m01, m23), d4 * d4);
            trow[i * COLS] = __expf(-mv * SIGMA_INV);  // consecutive-c -> conflict-free
        }
    } else if (t >= 256) {
        // ---- wave 4: rw power sums, overlapped with distance compute ----
        const int lane = t - 256;                 // 0..63
        double p1 = 0, p2 = 0, p3 = 0, p4 = 0;
        for (int i = lane; i < MC_; i += 64) {
            const double w  = (double)W[i];
            const double w2 = w * w;
            p1 += w; p2 += w2; p3 += w2 * w; p4 += w2 * w2;
        }
#pragma unroll
        for (int m = 32; m >= 1; m >>= 1) {       // butterfly: all lanes get sums
            p1 += __shfl_xor(p1, m);
            p2 += __shfl_xor(p2, m);
            p3 += __shfl_xor(p3, m);
            p4 += __shfl_xor(p4, m);
        }
        const double mc = (double)MC_;
        const double P  = 0.5 * (mc * mc - mc);
        const double S1 = mc * p2 - p1 * p1;
        const double Sq = mc * p4 - 4.0 * p3 * p1 + 3.0 * p2 * p2;
        const double mu = S1 / P;
        const float rw = (float)(Sq / P - mu * mu);
        if (lane < ROWS) tile[lane * COLS + C_] = rw;  // col 100, all 32 rows
    }
    __syncthreads();

    // ---- write phase: stream tile as aligned contiguous 16B nt stores ----
    const floatx4* lsrc = (const floatx4*)tile;
    floatx4* gdst = (floatx4*)(out + (size_t)n0 * COLS);  // blk*12928 B, 16B-aligned
    constexpr int NV = TILE / 4;  // 808 vectors = 2*320 + 168
#pragma unroll
    for (int q = 0; q < 2; ++q) {
        const int j = q * BLK + t;
        __builtin_nontemporal_store(lsrc[j], gdst + j);
    }
    {
        const int j = 2 * BLK + t;
        if (j < NV) __builtin_nontemporal_store(lsrc[j], gdst + j);
    }
}

extern "C" void kernel_launch(void* const* d_in, const int* in_sizes, int n_in,
                              void* d_out, int out_size, void* d_ws, size_t ws_size,
                              hipStream_t stream) {
    const float* f   = (const float*)d_in[0];   // (262144, 1) fp32
    const float* W   = (const float*)d_in[1];   // (100, 5, 1) fp32
    float*       out = (float*)d_out;           // (262144, 101) fp32

    affinity_kernel<<<N_ / ROWS, BLK, 0, stream>>>(f, W, out);
}